// Round 1
// baseline (917.440 us; speedup 1.0000x reference)
//
#include <hip/hip_runtime.h>

#define N_NODES 50000
#define N_EDGES 640000
#define HID 128
#define EDGE_DIM 32
#define NUM_GRAPHS 512
#define BN_EPS 1e-5f

// ---------------------------------------------------------------------------
// Precompute: Ea[d] = sum of edge_attr rows with dst==d ; deg[d] = edge count
// ---------------------------------------------------------------------------
__global__ void ea_deg_kernel(const float* __restrict__ edge_attr,
                              const int* __restrict__ eidx,
                              float* __restrict__ Ea, int* __restrict__ deg) {
    int tid = blockIdx.x * 256 + threadIdx.x;
    int e = tid >> 5, c = tid & 31;
    if (e >= N_EDGES) return;
    int d = eidx[N_EDGES + e];                 // dst row of edge_index
    unsafeAtomicAdd(&Ea[d * EDGE_DIM + c], edge_attr[e * EDGE_DIM + c]);
    if (c == 0) atomicAdd(&deg[d], 1);
}

// Single-block exclusive scan of deg -> rowp (N_NODES+1 entries)
__global__ void scan_kernel(const int* __restrict__ deg, int* __restrict__ rowp) {
    __shared__ int ssum[1024];
    int t = threadIdx.x;
    const int n = N_NODES;
    int strip = (n + 1023) >> 10;
    int s0 = t * strip, s1 = min(s0 + strip, n);
    int local = 0;
    for (int i = s0; i < s1; ++i) local += deg[i];
    ssum[t] = local;
    __syncthreads();
    for (int off = 1; off < 1024; off <<= 1) {
        int v = (t >= off) ? ssum[t - off] : 0;
        __syncthreads();
        ssum[t] += v;
        __syncthreads();
    }
    int excl = (t == 0) ? 0 : ssum[t - 1];
    for (int i = s0; i < s1; ++i) { rowp[i] = excl; excl += deg[i]; }
    if (t == 1023) rowp[n] = ssum[1023];
}

__global__ void fill_csr_kernel(const int* __restrict__ eidx,
                                const int* __restrict__ rowp,
                                int* __restrict__ cursor,
                                int* __restrict__ csr_src) {
    int e = blockIdx.x * 256 + threadIdx.x;
    if (e >= N_EDGES) return;
    int d = eidx[N_EDGES + e];
    int pos = atomicAdd(&cursor[d], 1);
    csr_src[rowp[d] + pos] = eidx[e];          // src row of edge_index
}

// ---------------------------------------------------------------------------
// Fused per-layer GEMM:
//   h[i]   = X[i] @ Wn + bn                       (K = 128)
//   acc[i] = h[i] + Ea[i] @ We + deg[i] * be      (K = 32)
// block = 256 threads, 32 rows/block; thread owns 4 rows x 4 cols
// ---------------------------------------------------------------------------
__global__ __launch_bounds__(256) void gemm_base_kernel(
        const float* __restrict__ X, const float* __restrict__ Wn,
        const float* __restrict__ bnb,
        const float* __restrict__ Ea, const float* __restrict__ We,
        const float* __restrict__ be, const int* __restrict__ deg,
        float* __restrict__ h, float* __restrict__ acc) {
    __shared__ float Xs[32][32];
    __shared__ float Ws[32][128];
    int tid = threadIdx.x;
    int r0b = blockIdx.x * 32;
    int c4 = (tid & 31) * 4;
    int rt = (tid >> 5) * 4;
    float4 accv[4];
    #pragma unroll
    for (int r = 0; r < 4; ++r) accv[r] = make_float4(0.f, 0.f, 0.f, 0.f);

    int lrow = tid >> 3;               // 0..31
    int lk4  = (tid & 7) * 4;          // 0,4,...,28
    int grow = min(r0b + lrow, N_NODES - 1);

    // ---- phase 1: X @ Wn, K = 128 ----
    for (int kb = 0; kb < 128; kb += 32) {
        __syncthreads();
        *(float4*)&Xs[lrow][lk4] = *(const float4*)&X[grow * 128 + kb + lk4];
        #pragma unroll
        for (int j = 0; j < 4; ++j) {
            int fi = tid + j * 256;
            int kk = fi >> 5, cc = (fi & 31) * 4;
            *(float4*)&Ws[kk][cc] = *(const float4*)&Wn[(kb + kk) * 128 + cc];
        }
        __syncthreads();
        #pragma unroll
        for (int k = 0; k < 32; ++k) {
            float4 w = *(float4*)&Ws[k][c4];
            #pragma unroll
            for (int r = 0; r < 4; ++r) {
                float xv = Xs[rt + r][k];
                accv[r].x += xv * w.x; accv[r].y += xv * w.y;
                accv[r].z += xv * w.z; accv[r].w += xv * w.w;
            }
        }
    }
    // h = partial + bn ; write h
    float4 bn4 = *(const float4*)&bnb[c4];
    #pragma unroll
    for (int r = 0; r < 4; ++r) {
        accv[r].x += bn4.x; accv[r].y += bn4.y;
        accv[r].z += bn4.z; accv[r].w += bn4.w;
        int row = r0b + rt + r;
        if (row < N_NODES) *(float4*)&h[row * 128 + c4] = accv[r];
    }
    // ---- phase 2: Ea @ We, K = 32 ----
    __syncthreads();
    *(float4*)&Xs[lrow][lk4] = *(const float4*)&Ea[grow * EDGE_DIM + lk4];
    #pragma unroll
    for (int j = 0; j < 4; ++j) {
        int fi = tid + j * 256;
        int kk = fi >> 5, cc = (fi & 31) * 4;
        *(float4*)&Ws[kk][cc] = *(const float4*)&We[kk * 128 + cc];
    }
    __syncthreads();
    #pragma unroll
    for (int k = 0; k < 32; ++k) {
        float4 w = *(float4*)&Ws[k][c4];
        #pragma unroll
        for (int r = 0; r < 4; ++r) {
            float xv = Xs[rt + r][k];
            accv[r].x += xv * w.x; accv[r].y += xv * w.y;
            accv[r].z += xv * w.z; accv[r].w += xv * w.w;
        }
    }
    float4 be4 = *(const float4*)&be[c4];
    #pragma unroll
    for (int r = 0; r < 4; ++r) {
        int row = r0b + rt + r;
        if (row < N_NODES) {
            float dg = (float)deg[row];
            accv[r].x += dg * be4.x; accv[r].y += dg * be4.y;
            accv[r].z += dg * be4.z; accv[r].w += dg * be4.w;
            *(float4*)&acc[row * 128 + c4] = accv[r];
        }
    }
}

// ---------------------------------------------------------------------------
// acc[d] += sum over CSR edges of h[src] ; one 128-thread block per node
// ---------------------------------------------------------------------------
__global__ void gather_kernel(const float* __restrict__ h,
                              const int* __restrict__ rowp,
                              const int* __restrict__ csr_src,
                              float* __restrict__ acc) {
    int node = blockIdx.x;
    int c = threadIdx.x;
    int beg = rowp[node], end = rowp[node + 1];
    float s = acc[node * 128 + c];
    for (int p = beg; p < end; ++p) {
        s += h[csr_src[p] * 128 + c];
    }
    acc[node * 128 + c] = s;
}

// per-column sum / sumsq over all nodes
__global__ void stats_kernel(const float* __restrict__ acc,
                             float* __restrict__ cs, float* __restrict__ cq) {
    int c = threadIdx.x & 127;
    int rg = threadIdx.x >> 7;
    float s = 0.f, q = 0.f;
    for (int r = blockIdx.x * 2 + rg; r < N_NODES; r += gridDim.x * 2) {
        float v = acc[r * 128 + c];
        s += v; q += v * v;
    }
    unsafeAtomicAdd(&cs[c], s);
    unsafeAtomicAdd(&cq[c], q);
}

__global__ void bnrelu_kernel(const float* __restrict__ acc,
                              const float* __restrict__ cs, const float* __restrict__ cq,
                              const float* __restrict__ gamma, const float* __restrict__ beta,
                              float* __restrict__ out) {
    int tid = blockIdx.x * 256 + threadIdx.x;
    if (tid >= N_NODES * 32) return;
    int r = tid >> 5, c4 = (tid & 31) * 4;
    const float invN = 1.0f / (float)N_NODES;
    float4 v = *(const float4*)&acc[r * 128 + c4];
    float4 s = *(const float4*)&cs[c4];
    float4 q = *(const float4*)&cq[c4];
    float4 g = *(const float4*)&gamma[c4];
    float4 b = *(const float4*)&beta[c4];
    float4 res;
    float m, var, sc;
    m = s.x * invN; var = q.x * invN - m * m; sc = g.x * rsqrtf(var + BN_EPS);
    res.x = fmaxf(0.f, (v.x - m) * sc + b.x);
    m = s.y * invN; var = q.y * invN - m * m; sc = g.y * rsqrtf(var + BN_EPS);
    res.y = fmaxf(0.f, (v.y - m) * sc + b.y);
    m = s.z * invN; var = q.z * invN - m * m; sc = g.z * rsqrtf(var + BN_EPS);
    res.z = fmaxf(0.f, (v.z - m) * sc + b.z);
    m = s.w * invN; var = q.w * invN - m * m; sc = g.w * rsqrtf(var + BN_EPS);
    res.w = fmaxf(0.f, (v.w - m) * sc + b.w);
    *(float4*)&out[r * 128 + c4] = res;
}

__global__ void pool_kernel(const float* __restrict__ x, const int* __restrict__ batch,
                            float* __restrict__ pooled, float* __restrict__ pcnt) {
    int tid = blockIdx.x * 256 + threadIdx.x;
    if (tid >= N_NODES * 32) return;
    int r = tid >> 5, c4 = (tid & 31) * 4;
    int g = batch[r];
    float4 v = *(const float4*)&x[r * 128 + c4];
    unsafeAtomicAdd(&pooled[g * 128 + c4 + 0], v.x);
    unsafeAtomicAdd(&pooled[g * 128 + c4 + 1], v.y);
    unsafeAtomicAdd(&pooled[g * 128 + c4 + 2], v.z);
    unsafeAtomicAdd(&pooled[g * 128 + c4 + 3], v.w);
    if (c4 == 0) unsafeAtomicAdd(&pcnt[g], 1.0f);
}

__global__ void fc_kernel(const float* __restrict__ pooled, const float* __restrict__ pcnt,
                          const float* __restrict__ Wfc, const float* __restrict__ bfc,
                          float* __restrict__ out) {
    int tid = blockIdx.x * 256 + threadIdx.x;
    if (tid >= NUM_GRAPHS * 2) return;
    int g = tid >> 1, o = tid & 1;
    float s = 0.f;
    for (int c = 0; c < 128; ++c) s += pooled[g * 128 + c] * Wfc[c * 2 + o];
    out[tid] = s / fmaxf(pcnt[g], 1.0f) + bfc[o];
}

// ---------------------------------------------------------------------------
extern "C" void kernel_launch(void* const* d_in, const int* in_sizes, int n_in,
                              void* d_out, int out_size, void* d_ws, size_t ws_size,
                              hipStream_t stream) {
    const float* x         = (const float*)d_in[0];
    const float* edge_attr = (const float*)d_in[1];
    const int*   eidx      = (const int*)d_in[2];
    const int*   batch     = (const int*)d_in[3];
    const float* Wn[3]  = {(const float*)d_in[4],  (const float*)d_in[8],  (const float*)d_in[12]};
    const float* bnb[3] = {(const float*)d_in[5],  (const float*)d_in[9],  (const float*)d_in[13]};
    const float* We[3]  = {(const float*)d_in[6],  (const float*)d_in[10], (const float*)d_in[14]};
    const float* be[3]  = {(const float*)d_in[7],  (const float*)d_in[11], (const float*)d_in[15]};
    const float* gm[3]  = {(const float*)d_in[16], (const float*)d_in[18], (const float*)d_in[20]};
    const float* bt[3]  = {(const float*)d_in[17], (const float*)d_in[19], (const float*)d_in[21]};
    const float* Wfc = (const float*)d_in[22];
    const float* bfc = (const float*)d_in[23];
    float* out = (float*)d_out;

    char* p = (char*)d_ws;
    auto alloc = [&](size_t bytes) {
        char* q = p;
        p += (bytes + 255) & ~size_t(255);
        return q;
    };
    float* Ea     = (float*)alloc(sizeof(float) * N_NODES * EDGE_DIM);
    float* hbuf   = (float*)alloc(sizeof(float) * N_NODES * HID);
    float* accbuf = (float*)alloc(sizeof(float) * N_NODES * HID);
    float* xbuf   = (float*)alloc(sizeof(float) * N_NODES * HID);
    float* cs     = (float*)alloc(sizeof(float) * HID);      // cs and cq contiguous
    float* cq     = (float*)alloc(sizeof(float) * HID);
    float* pooled = (float*)alloc(sizeof(float) * NUM_GRAPHS * HID);
    float* pcnt   = (float*)alloc(sizeof(float) * NUM_GRAPHS);
    int*   deg    = (int*)alloc(sizeof(int) * N_NODES);
    int*   rowp   = (int*)alloc(sizeof(int) * (N_NODES + 1));
    int*   cursor = (int*)alloc(sizeof(int) * N_NODES);
    int*   csr    = (int*)alloc(sizeof(int) * N_EDGES);

    // zero all accumulation buffers every call (harness does not re-poison)
    hipMemsetAsync(Ea, 0, sizeof(float) * N_NODES * EDGE_DIM, stream);
    hipMemsetAsync(pooled, 0, sizeof(float) * NUM_GRAPHS * HID, stream);
    hipMemsetAsync(pcnt, 0, sizeof(float) * NUM_GRAPHS, stream);
    hipMemsetAsync(deg, 0, sizeof(int) * N_NODES, stream);
    hipMemsetAsync(cursor, 0, sizeof(int) * N_NODES, stream);

    ea_deg_kernel<<<(N_EDGES * 32 + 255) / 256, 256, 0, stream>>>(edge_attr, eidx, Ea, deg);
    scan_kernel<<<1, 1024, 0, stream>>>(deg, rowp);
    fill_csr_kernel<<<(N_EDGES + 255) / 256, 256, 0, stream>>>(eidx, rowp, cursor, csr);

    const float* X = x;
    for (int l = 0; l < 3; ++l) {
        hipMemsetAsync(cs, 0, sizeof(float) * HID * 2, stream);  // cs + cq
        gemm_base_kernel<<<(N_NODES + 31) / 32, 256, 0, stream>>>(
            X, Wn[l], bnb[l], Ea, We[l], be[l], deg, hbuf, accbuf);
        gather_kernel<<<N_NODES, 128, 0, stream>>>(hbuf, rowp, csr, accbuf);
        stats_kernel<<<256, 256, 0, stream>>>(accbuf, cs, cq);
        bnrelu_kernel<<<(N_NODES * 32 + 255) / 256, 256, 0, stream>>>(
            accbuf, cs, cq, gm[l], bt[l], xbuf);
        X = xbuf;
    }
    pool_kernel<<<(N_NODES * 32 + 255) / 256, 256, 0, stream>>>(xbuf, batch, pooled, pcnt);
    fc_kernel<<<4, 256, 0, stream>>>(pooled, pcnt, Wfc, bfc, out);
}

// Round 2
// 773.183 us; speedup vs baseline: 1.1866x; 1.1866x over previous
//
#include <hip/hip_runtime.h>

#define N_NODES 50000
#define N_EDGES 640000
#define HID 128
#define EDGE_DIM 32
#define NUM_GRAPHS 512
#define BN_EPS 1e-5f

// ---------------------------------------------------------------------------
// Precompute: Ea[d] = sum of edge_attr rows with dst==d ; deg[d] = edge count
// ---------------------------------------------------------------------------
__global__ void ea_deg_kernel(const float* __restrict__ edge_attr,
                              const int* __restrict__ eidx,
                              float* __restrict__ Ea, int* __restrict__ deg) {
    int tid = blockIdx.x * 256 + threadIdx.x;
    int e = tid >> 5, c = tid & 31;
    if (e >= N_EDGES) return;
    int d = eidx[N_EDGES + e];                 // dst row of edge_index
    unsafeAtomicAdd(&Ea[d * EDGE_DIM + c], edge_attr[e * EDGE_DIM + c]);
    if (c == 0) atomicAdd(&deg[d], 1);
}

// Single-block exclusive scan of deg -> rowp (N_NODES+1 entries)
__global__ void scan_kernel(const int* __restrict__ deg, int* __restrict__ rowp) {
    __shared__ int ssum[1024];
    int t = threadIdx.x;
    const int n = N_NODES;
    int strip = (n + 1023) >> 10;
    int s0 = t * strip, s1 = min(s0 + strip, n);
    int local = 0;
    for (int i = s0; i < s1; ++i) local += deg[i];
    ssum[t] = local;
    __syncthreads();
    for (int off = 1; off < 1024; off <<= 1) {
        int v = (t >= off) ? ssum[t - off] : 0;
        __syncthreads();
        ssum[t] += v;
        __syncthreads();
    }
    int excl = (t == 0) ? 0 : ssum[t - 1];
    for (int i = s0; i < s1; ++i) { rowp[i] = excl; excl += deg[i]; }
    if (t == 1023) rowp[n] = ssum[1023];
}

__global__ void fill_csr_kernel(const int* __restrict__ eidx,
                                const int* __restrict__ rowp,
                                int* __restrict__ cursor,
                                int* __restrict__ csr_src) {
    int e = blockIdx.x * 256 + threadIdx.x;
    if (e >= N_EDGES) return;
    int d = eidx[N_EDGES + e];
    int pos = atomicAdd(&cursor[d], 1);
    csr_src[rowp[d] + pos] = eidx[e];          // src row of edge_index
}

// ---------------------------------------------------------------------------
// Fused per-layer GEMM (optionally applying BN+ReLU of the PREVIOUS layer to
// the X tile as it is loaded):
//   xin    = BN ? relu(X*scale + shift) : X
//   h[i]   = xin[i] @ Wn + bn                     (K = 128)
//   acc[i] = h[i] + Ea[i] @ We + deg[i] * be      (K = 32)
// block = 256 threads, 32 rows/block; thread owns 4 rows x 4 cols
// ---------------------------------------------------------------------------
template <bool BN>
__global__ __launch_bounds__(256) void gemm_base_kernel(
        const float* __restrict__ X, const float* __restrict__ Wn,
        const float* __restrict__ bnb,
        const float* __restrict__ Ea, const float* __restrict__ We,
        const float* __restrict__ be, const int* __restrict__ deg,
        const float* __restrict__ scale, const float* __restrict__ shift,
        float* __restrict__ h, float* __restrict__ acc) {
    __shared__ float Xs[32][32];
    __shared__ float Ws[32][128];
    int tid = threadIdx.x;
    int r0b = blockIdx.x * 32;
    int c4 = (tid & 31) * 4;
    int rt = (tid >> 5) * 4;
    float4 accv[4];
    #pragma unroll
    for (int r = 0; r < 4; ++r) accv[r] = make_float4(0.f, 0.f, 0.f, 0.f);

    int lrow = tid >> 3;               // 0..31
    int lk4  = (tid & 7) * 4;          // 0,4,...,28
    int grow = min(r0b + lrow, N_NODES - 1);

    // ---- phase 1: X @ Wn, K = 128 ----
    for (int kb = 0; kb < 128; kb += 32) {
        __syncthreads();
        float4 xv4 = *(const float4*)&X[grow * 128 + kb + lk4];
        if (BN) {
            float4 sc4 = *(const float4*)&scale[kb + lk4];
            float4 sh4 = *(const float4*)&shift[kb + lk4];
            xv4.x = fmaxf(0.f, xv4.x * sc4.x + sh4.x);
            xv4.y = fmaxf(0.f, xv4.y * sc4.y + sh4.y);
            xv4.z = fmaxf(0.f, xv4.z * sc4.z + sh4.z);
            xv4.w = fmaxf(0.f, xv4.w * sc4.w + sh4.w);
        }
        *(float4*)&Xs[lrow][lk4] = xv4;
        #pragma unroll
        for (int j = 0; j < 4; ++j) {
            int fi = tid + j * 256;
            int kk = fi >> 5, cc = (fi & 31) * 4;
            *(float4*)&Ws[kk][cc] = *(const float4*)&Wn[(kb + kk) * 128 + cc];
        }
        __syncthreads();
        #pragma unroll
        for (int k = 0; k < 32; ++k) {
            float4 w = *(float4*)&Ws[k][c4];
            #pragma unroll
            for (int r = 0; r < 4; ++r) {
                float xv = Xs[rt + r][k];
                accv[r].x += xv * w.x; accv[r].y += xv * w.y;
                accv[r].z += xv * w.z; accv[r].w += xv * w.w;
            }
        }
    }
    // h = partial + bn ; write h
    float4 bn4 = *(const float4*)&bnb[c4];
    #pragma unroll
    for (int r = 0; r < 4; ++r) {
        accv[r].x += bn4.x; accv[r].y += bn4.y;
        accv[r].z += bn4.z; accv[r].w += bn4.w;
        int row = r0b + rt + r;
        if (row < N_NODES) *(float4*)&h[row * 128 + c4] = accv[r];
    }
    // ---- phase 2: Ea @ We, K = 32 ----
    __syncthreads();
    *(float4*)&Xs[lrow][lk4] = *(const float4*)&Ea[grow * EDGE_DIM + lk4];
    #pragma unroll
    for (int j = 0; j < 4; ++j) {
        int fi = tid + j * 256;
        int kk = fi >> 5, cc = (fi & 31) * 4;
        *(float4*)&Ws[kk][cc] = *(const float4*)&We[kk * 128 + cc];
    }
    __syncthreads();
    #pragma unroll
    for (int k = 0; k < 32; ++k) {
        float4 w = *(float4*)&Ws[k][c4];
        #pragma unroll
        for (int r = 0; r < 4; ++r) {
            float xv = Xs[rt + r][k];
            accv[r].x += xv * w.x; accv[r].y += xv * w.y;
            accv[r].z += xv * w.z; accv[r].w += xv * w.w;
        }
    }
    float4 be4 = *(const float4*)&be[c4];
    #pragma unroll
    for (int r = 0; r < 4; ++r) {
        int row = r0b + rt + r;
        if (row < N_NODES) {
            float dg = (float)deg[row];
            accv[r].x += dg * be4.x; accv[r].y += dg * be4.y;
            accv[r].z += dg * be4.z; accv[r].w += dg * be4.w;
            *(float4*)&acc[row * 128 + c4] = accv[r];
        }
    }
}

// ---------------------------------------------------------------------------
// acc[d] += sum over CSR edges of h[src] ; one 128-thread block per node
// ---------------------------------------------------------------------------
__global__ void gather_kernel(const float* __restrict__ h,
                              const int* __restrict__ rowp,
                              const int* __restrict__ csr_src,
                              float* __restrict__ acc) {
    int node = blockIdx.x;
    int c = threadIdx.x;
    int beg = rowp[node], end = rowp[node + 1];
    float s = acc[node * 128 + c];
    for (int p = beg; p < end; ++p) {
        s += h[csr_src[p] * 128 + c];
    }
    acc[node * 128 + c] = s;
}

// per-column sum / sumsq over all nodes
__global__ void stats_kernel(const float* __restrict__ acc,
                             float* __restrict__ cs, float* __restrict__ cq) {
    int c = threadIdx.x & 127;
    int rg = threadIdx.x >> 7;
    float s = 0.f, q = 0.f;
    for (int r = blockIdx.x * 2 + rg; r < N_NODES; r += gridDim.x * 2) {
        float v = acc[r * 128 + c];
        s += v; q += v * v;
    }
    unsafeAtomicAdd(&cs[c], s);
    unsafeAtomicAdd(&cq[c], q);
}

// scale/shift from column stats: y = x*scale[c] + shift[c]
__global__ void prep_bn_kernel(const float* __restrict__ cs, const float* __restrict__ cq,
                               const float* __restrict__ gamma, const float* __restrict__ beta,
                               float* __restrict__ scale, float* __restrict__ shift) {
    int c = threadIdx.x;
    const float invN = 1.0f / (float)N_NODES;
    float m = cs[c] * invN;
    float var = cq[c] * invN - m * m;
    float sc = gamma[c] * rsqrtf(var + BN_EPS);
    scale[c] = sc;
    shift[c] = beta[c] - m * sc;
}

// ---------------------------------------------------------------------------
// One block per graph (batch is sorted): binary-search node range, apply
// layer-3 BN+ReLU inline, mean-pool, then the 128->2 FC. No atomics.
// ---------------------------------------------------------------------------
__global__ __launch_bounds__(256) void pool_fc_kernel(
        const float* __restrict__ acc,
        const float* __restrict__ scale, const float* __restrict__ shift,
        const int* __restrict__ batch,
        const float* __restrict__ Wfc, const float* __restrict__ bfc,
        float* __restrict__ out) {
    __shared__ float ps[256];
    int g = blockIdx.x;
    int lo = 0, hi = N_NODES;
    while (lo < hi) { int mid = (lo + hi) >> 1; if (batch[mid] < g) lo = mid + 1; else hi = mid; }
    int start = lo;
    hi = N_NODES;
    while (lo < hi) { int mid = (lo + hi) >> 1; if (batch[mid] < g + 1) lo = mid + 1; else hi = mid; }
    int end = lo;

    int c = threadIdx.x & 127;
    int half = threadIdx.x >> 7;
    float sc = scale[c], sh = shift[c];
    float s = 0.f;
    for (int r = start + half; r < end; r += 2)
        s += fmaxf(0.f, acc[r * 128 + c] * sc + sh);
    ps[threadIdx.x] = s;
    __syncthreads();
    if (half == 0)
        ps[c] = (ps[c] + ps[c + 128]) / fmaxf((float)(end - start), 1.0f);
    __syncthreads();
    if (threadIdx.x < 2) {
        int o = threadIdx.x;
        float t = 0.f;
        #pragma unroll 16
        for (int cc = 0; cc < 128; ++cc) t += ps[cc] * Wfc[cc * 2 + o];
        out[g * 2 + o] = t + bfc[o];
    }
}

// ---------------------------------------------------------------------------
extern "C" void kernel_launch(void* const* d_in, const int* in_sizes, int n_in,
                              void* d_out, int out_size, void* d_ws, size_t ws_size,
                              hipStream_t stream) {
    const float* x         = (const float*)d_in[0];
    const float* edge_attr = (const float*)d_in[1];
    const int*   eidx      = (const int*)d_in[2];
    const int*   batch     = (const int*)d_in[3];
    const float* Wn[3]  = {(const float*)d_in[4],  (const float*)d_in[8],  (const float*)d_in[12]};
    const float* bnb[3] = {(const float*)d_in[5],  (const float*)d_in[9],  (const float*)d_in[13]};
    const float* We[3]  = {(const float*)d_in[6],  (const float*)d_in[10], (const float*)d_in[14]};
    const float* be[3]  = {(const float*)d_in[7],  (const float*)d_in[11], (const float*)d_in[15]};
    const float* gm[3]  = {(const float*)d_in[16], (const float*)d_in[18], (const float*)d_in[20]};
    const float* bt[3]  = {(const float*)d_in[17], (const float*)d_in[19], (const float*)d_in[21]};
    const float* Wfc = (const float*)d_in[22];
    const float* bfc = (const float*)d_in[23];
    float* out = (float*)d_out;

    char* p = (char*)d_ws;
    auto alloc = [&](size_t bytes) {
        char* q = p;
        p += (bytes + 255) & ~size_t(255);
        return q;
    };
    float* Ea     = (float*)alloc(sizeof(float) * N_NODES * EDGE_DIM);
    float* hbuf   = (float*)alloc(sizeof(float) * N_NODES * HID);
    float* accA   = (float*)alloc(sizeof(float) * N_NODES * HID);
    float* accB   = (float*)alloc(sizeof(float) * N_NODES * HID);
    float* cs     = (float*)alloc(sizeof(float) * HID);      // cs and cq contiguous
    float* cq     = (float*)alloc(sizeof(float) * HID);
    float* scale  = (float*)alloc(sizeof(float) * HID);
    float* shift  = (float*)alloc(sizeof(float) * HID);
    int*   deg    = (int*)alloc(sizeof(int) * N_NODES);
    int*   rowp   = (int*)alloc(sizeof(int) * (N_NODES + 1));
    int*   cursor = (int*)alloc(sizeof(int) * N_NODES);
    int*   csr    = (int*)alloc(sizeof(int) * N_EDGES);

    // zero all accumulation buffers every call (harness does not re-poison)
    hipMemsetAsync(Ea, 0, sizeof(float) * N_NODES * EDGE_DIM, stream);
    hipMemsetAsync(deg, 0, sizeof(int) * N_NODES, stream);
    hipMemsetAsync(cursor, 0, sizeof(int) * N_NODES, stream);

    ea_deg_kernel<<<(N_EDGES * 32 + 255) / 256, 256, 0, stream>>>(edge_attr, eidx, Ea, deg);
    scan_kernel<<<1, 1024, 0, stream>>>(deg, rowp);
    fill_csr_kernel<<<(N_EDGES + 255) / 256, 256, 0, stream>>>(eidx, rowp, cursor, csr);

    float* accs[3] = {accA, accB, accA};
    const int ngrid = (N_NODES + 31) / 32;
    const float* X = x;
    for (int l = 0; l < 3; ++l) {
        hipMemsetAsync(cs, 0, sizeof(float) * HID * 2, stream);  // cs + cq
        float* acc = accs[l];
        if (l == 0) {
            gemm_base_kernel<false><<<ngrid, 256, 0, stream>>>(
                X, Wn[l], bnb[l], Ea, We[l], be[l], deg, nullptr, nullptr, hbuf, acc);
        } else {
            gemm_base_kernel<true><<<ngrid, 256, 0, stream>>>(
                X, Wn[l], bnb[l], Ea, We[l], be[l], deg, scale, shift, hbuf, acc);
        }
        gather_kernel<<<N_NODES, 128, 0, stream>>>(hbuf, rowp, csr, acc);
        stats_kernel<<<256, 256, 0, stream>>>(acc, cs, cq);
        prep_bn_kernel<<<1, 128, 0, stream>>>(cs, cq, gm[l], bt[l], scale, shift);
        X = acc;
    }
    pool_fc_kernel<<<NUM_GRAPHS, 256, 0, stream>>>(
        accs[2], scale, shift, batch, Wfc, bfc, out);
}